// Round 1
// baseline (3449.828 us; speedup 1.0000x reference)
//
#include <hip/hip_runtime.h>
#include <hip/hip_bf16.h>
#include <math.h>

#define H 2048
#define V 32000
#define T 512
#define TOK 2048        // B*T tokens per model
#define BM 64
#define BN 64
#define BK 32
#define NCH (V / BN)    // 500 V-chunks
#define IGN (-100)

typedef __attribute__((ext_vector_type(8))) short short8;
typedef __attribute__((ext_vector_type(4))) float f32x4;

__device__ __forceinline__ unsigned short f2bf(float f) {
    unsigned int u = __float_as_uint(f);
    u += 0x7fffu + ((u >> 16) & 1u);   // round-to-nearest-even
    return (unsigned short)(u >> 16);
}

// ---------------------------------------------------------------------------
// Kernel 1: fused GEMM tile + per-(token, v-chunk) partial logsumexp.
// grid = (tokTiles=32, vChunks=500, models=2), block = 256 (4 waves).
// Token-tile is the fastest grid dim so consecutive blocks share a W slab.
// ---------------------------------------------------------------------------
__global__ __launch_bounds__(256) void gemm_partial(
    const float* __restrict__ X,  const float* __restrict__ Xr,
    const float* __restrict__ Wp, const float* __restrict__ Wr,
    float* __restrict__ ms_m, float* __restrict__ ms_s)
{
    __shared__ float smemF[64 * 65];          // 16640 B; also used for staging
    short* smemS = (short*)smemF;
    short* ldsA = smemS;                      // 64 x 40 bf16 (pad 32->40)
    short* ldsB = smemS + 64 * 40;            // 64 x 40 bf16

    const int tid     = threadIdx.x;
    const int model   = blockIdx.z;
    const int tokBase = blockIdx.x * BM;
    const int vBase   = blockIdx.y * BN;

    const float* __restrict__ Xp = model ? Xr : X;
    const float* __restrict__ Wm = model ? Wr : Wp;

    const int lane = tid & 63;
    const int wave = tid >> 6;
    const int q    = lane >> 4;
    const int rl   = lane & 15;
    const int m0   = (wave >> 1) * 32;
    const int n0   = (wave & 1) * 32;

    f32x4 acc[2][2];
    for (int a = 0; a < 2; a++)
        for (int b = 0; b < 2; b++)
            acc[a][b] = (f32x4){0.f, 0.f, 0.f, 0.f};

    for (int kk = 0; kk < H / BK; kk++) {
        const int k0 = kk * BK;
        __syncthreads();
        // stage A (64x32 f32) and B (64x32 f32), converting to bf16
        for (int rep = 0; rep < 2; rep++) {
            int i   = tid + rep * 256;        // 0..511 float4 slots
            int row = i >> 3;
            int cf  = (i & 7) * 4;
            const float4 va = *(const float4*)(Xp + (size_t)(tokBase + row) * H + k0 + cf);
            short* pa = ldsA + row * 40 + cf;
            pa[0] = (short)f2bf(va.x); pa[1] = (short)f2bf(va.y);
            pa[2] = (short)f2bf(va.z); pa[3] = (short)f2bf(va.w);
            const float4 vb = *(const float4*)(Wm + (size_t)(vBase + row) * H + k0 + cf);
            short* pb = ldsB + row * 40 + cf;
            pb[0] = (short)f2bf(vb.x); pb[1] = (short)f2bf(vb.y);
            pb[2] = (short)f2bf(vb.z); pb[3] = (short)f2bf(vb.w);
        }
        __syncthreads();

        short8 aF[2], bF[2];
        for (int im = 0; im < 2; im++)
            aF[im] = *(const short8*)(ldsA + (m0 + im * 16 + rl) * 40 + q * 8);
        for (int in = 0; in < 2; in++)
            bF[in] = *(const short8*)(ldsB + (n0 + in * 16 + rl) * 40 + q * 8);

        for (int im = 0; im < 2; im++)
            for (int in = 0; in < 2; in++)
                acc[im][in] = __builtin_amdgcn_mfma_f32_16x16x32_bf16(
                    aF[im], bF[in], acc[im][in], 0, 0, 0);
    }

    __syncthreads();
    // dump 64x64 logit tile to LDS (stride 65 to avoid bank conflicts)
    for (int im = 0; im < 2; im++)
        for (int in = 0; in < 2; in++)
            for (int i = 0; i < 4; i++)
                smemF[(m0 + im * 16 + q * 4 + i) * 65 + (n0 + in * 16 + rl)] =
                    acc[im][in][i];
    __syncthreads();

    if (tid < 64) {
        const float* rowp = smemF + tid * 65;
        float m = -INFINITY;
        for (int j = 0; j < 64; j++) m = fmaxf(m, rowp[j]);
        float s = 0.f;
        for (int j = 0; j < 64; j++) s += __expf(rowp[j] - m);
        size_t idx = ((size_t)model * TOK + (tokBase + tid)) * NCH + blockIdx.y;
        ms_m[idx] = m;
        ms_s[idx] = s;
    }
}

// ---------------------------------------------------------------------------
// Kernel 2: label logit per (model, token). One wave per token.
// grid = 1024 blocks x 256 threads (4 waves each) -> 4096 waves.
// ---------------------------------------------------------------------------
__global__ __launch_bounds__(256) void label_logit(
    const float* __restrict__ X,  const float* __restrict__ Xr,
    const float* __restrict__ Wp, const float* __restrict__ Wr,
    const int* __restrict__ y, float* __restrict__ z)
{
    int id    = blockIdx.x * 4 + (threadIdx.x >> 6);  // 0..4095
    int lane  = threadIdx.x & 63;
    int model = id >> 11;
    int token = id & 2047;
    const float* __restrict__ Xp = model ? Xr : X;
    const float* __restrict__ Wm = model ? Wr : Wp;
    int lab = y[token];
    float sum = 0.f;
    if (lab != IGN) {
        const float* xp = Xp + (size_t)token * H;
        const float* wp = Wm + (size_t)lab * H;
        for (int c = lane; c < H; c += 64) sum += xp[c] * wp[c];
    }
    for (int off = 32; off; off >>= 1) sum += __shfl_down(sum, off);
    if (lane == 0) z[id] = sum;
}

// ---------------------------------------------------------------------------
// Kernel 3: combine 500 partial (m,s) per (model,token) -> logp.
// grid = 4096 blocks x 256 threads.
// ---------------------------------------------------------------------------
__global__ __launch_bounds__(256) void lse_logp(
    const float* __restrict__ ms_m, const float* __restrict__ ms_s,
    const float* __restrict__ z, float* __restrict__ logp)
{
    int id = blockIdx.x;   // 0..4095
    int t  = threadIdx.x;
    __shared__ float red[256];
    const float* mrow = ms_m + (size_t)id * NCH;
    const float* srow = ms_s + (size_t)id * NCH;

    float m = -INFINITY;
    for (int c = t; c < NCH; c += 256) m = fmaxf(m, mrow[c]);
    red[t] = m; __syncthreads();
    for (int w = 128; w; w >>= 1) {
        if (t < w) red[t] = fmaxf(red[t], red[t + w]);
        __syncthreads();
    }
    float M = red[0]; __syncthreads();

    float s = 0.f;
    for (int c = t; c < NCH; c += 256) s += srow[c] * __expf(mrow[c] - M);
    red[t] = s; __syncthreads();
    for (int w = 128; w; w >>= 1) {
        if (t < w) red[t] += red[t + w];
        __syncthreads();
    }
    if (t == 0) {
        float lse = M + logf(red[0]);
        logp[id] = z[id] - lse;
    }
}

// ---------------------------------------------------------------------------
// Kernel 4: batch means + SPPO-hard loss. 1 block, 64 threads.
// ---------------------------------------------------------------------------
__global__ void final_loss(const float* __restrict__ logp,
                           const int* __restrict__ y,
                           float* __restrict__ out)
{
    __shared__ float lp[8];
    int t = threadIdx.x;
    if (t < 8) {
        int model = t >> 2, b = t & 3;
        float s = 0.f, cnt = 0.f;
        for (int i = 0; i < T; i++) {
            int tok = b * T + i;
            if (y[tok] != IGN) { s += logp[model * TOK + tok]; cnt += 1.f; }
        }
        lp[t] = s / cnt;
    }
    __syncthreads();
    if (t == 0) {
        float a0 = lp[0] - lp[4], a1 = lp[1] - lp[5];   // chosen: batches 0,1
        float b0 = lp[2] - lp[6], b1 = lp[3] - lp[7];   // rejected: batches 2,3
        float l0 = (a0 - 5.f) * (a0 - 5.f) + (b0 + 5.f) * (b0 + 5.f);
        float l1 = (a1 - 5.f) * (a1 - 5.f) + (b1 + 5.f) * (b1 + 5.f);
        out[0] = -(l0 + l1) * 0.5f;    // 0*ALPHA - mean(losses)
    }
}

extern "C" void kernel_launch(void* const* d_in, const int* in_sizes, int n_in,
                              void* d_out, int out_size, void* d_ws, size_t ws_size,
                              hipStream_t stream)
{
    const float* X  = (const float*)d_in[0];
    const float* Xr = (const float*)d_in[1];
    const int*   y  = (const int*)d_in[2];
    const float* Wp = (const float*)d_in[3];
    const float* Wr = (const float*)d_in[4];
    float* out = (float*)d_out;

    // workspace layout (floats)
    float* ws   = (float*)d_ws;
    const size_t msElems = (size_t)2 * TOK * NCH;   // 2,048,000
    float* ms_m = ws;
    float* ms_s = ws + msElems;
    float* z    = ws + 2 * msElems;
    float* logp = z + 2 * TOK;

    dim3 g1(TOK / BM, V / BN, 2);          // (32, 500, 2)
    gemm_partial<<<g1, 256, 0, stream>>>(X, Xr, Wp, Wr, ms_m, ms_s);

    label_logit<<<(2 * TOK) / 4, 256, 0, stream>>>(X, Xr, Wp, Wr, y, z);

    lse_logp<<<2 * TOK, 256, 0, stream>>>(ms_m, ms_s, z, logp);

    final_loss<<<1, 64, 0, stream>>>(logp, y, out);
}

// Round 2
// 1299.103 us; speedup vs baseline: 2.6555x; 2.6555x over previous
//
#include <hip/hip_runtime.h>
#include <hip/hip_bf16.h>
#include <math.h>

#define H 2048
#define V 32000
#define T 512
#define TOK 2048        // B*T tokens per model
#define IGN (-100)

// round-1 fallback tile
#define BM 64
#define BN 64
#define BK 32
#define NCH (V / BN)    // 500 chunks of 64 cols (shared by both paths)

// fast-path tile
#define GBM 128
#define GBN 128
#define GBK 32

typedef unsigned short u16;
typedef __attribute__((ext_vector_type(8))) short short8;
typedef __attribute__((ext_vector_type(4))) float f32x4;

__device__ __forceinline__ u16 f2bf(float f) {
    unsigned int u = __float_as_uint(f);
    u += 0x7fffu + ((u >> 16) & 1u);   // round-to-nearest-even
    return (u16)(u >> 16);
}

#define GLD16(gp, lp) __builtin_amdgcn_global_load_lds( \
    (const __attribute__((address_space(1))) unsigned int*)(gp), \
    (__attribute__((address_space(3))) unsigned int*)(lp), 16, 0, 0)

// ---------------------------------------------------------------------------
// Convert f32 -> bf16 (RNE), vectorized. n4 = element count / 4.
// ---------------------------------------------------------------------------
__global__ __launch_bounds__(256) void f32_to_bf16(
    const float* __restrict__ src, u16* __restrict__ dst, int n4)
{
    for (int i = blockIdx.x * 256 + threadIdx.x; i < n4; i += gridDim.x * 256) {
        float4 v = ((const float4*)src)[i];
        ushort4 o;
        o.x = f2bf(v.x); o.y = f2bf(v.y); o.z = f2bf(v.z); o.w = f2bf(v.w);
        ((ushort4*)dst)[i] = o;
    }
}

// ---------------------------------------------------------------------------
// Fast path: m97-structure bf16 GEMM, 128x128 tile, BK=32, global_load_lds
// staging with XOR bank swizzle, fused per-(row,64col) partial softmax.
// grid = (16 tokTiles, 250 vTiles, 2 models), block = 256 (4 waves, 2x2).
// ---------------------------------------------------------------------------
__global__ __launch_bounds__(256) void gemm_bf16(
    const u16* __restrict__ Xb, const u16* __restrict__ Wb,
    float* __restrict__ ms_m, float* __restrict__ ms_s)
{
    // A tile: 128x32 bf16 = 4096 shorts (512 groups of 8), then B tile.
    __shared__ __align__(16) u16 lds[2 * GBM * GBK];

    const int tid  = threadIdx.x;
    const int wave = tid >> 6;
    const int lane = tid & 63;
    const int q    = lane >> 4;
    const int rl   = lane & 15;
    const int m0   = (wave >> 1) * 64;
    const int n0   = (wave & 1) * 64;
    const int model = blockIdx.z;
    const size_t tokBase = (size_t)blockIdx.x * GBM;
    const size_t vBase   = (size_t)blockIdx.y * GBN;

    const u16* __restrict__ A  = Xb + (size_t)model * (2048ULL * H) + tokBase * H;
    const u16* __restrict__ Bm = Wb + (size_t)model * ((size_t)V * H) + vBase * H;

    // Staging: linear group G in [0,512); physical LDS slot G holds logical
    // (row r = G>>2, kgroup g = (G&3) ^ ((r>>1)&3)).  Lane-contiguous in LDS
    // (global_load_lds requirement); swizzle realized by the global address.
    const int G0 = wave * 128 + lane;
    const int G1 = G0 + 64;
    const int r0 = G0 >> 2, g0 = (((G0 & 3) ^ ((r0 >> 1) & 3)) << 3);
    const int r1 = G1 >> 2, g1 = (((G1 & 3) ^ ((r1 >> 1) & 3)) << 3);
    const u16* a0 = A  + (size_t)r0 * H + g0;
    const u16* a1 = A  + (size_t)r1 * H + g1;
    const u16* b0 = Bm + (size_t)r0 * H + g0;
    const u16* b1 = Bm + (size_t)r1 * H + g1;
    u16* lA0 = lds + wave * 1024;            // slot base * 8 shorts
    u16* lA1 = lA0 + 512;
    u16* lB0 = lds + 4096 + wave * 1024;
    u16* lB1 = lB0 + 512;

    // Fragment LDS offsets (shorts): phys slot = r*4 + (q ^ ((r>>1)&3))
    int aOff[4], bOff[4];
#pragma unroll
    for (int im = 0; im < 4; im++) {
        int r = m0 + im * 16 + rl;
        aOff[im] = r * 32 + ((q ^ ((r >> 1) & 3)) << 3);
    }
#pragma unroll
    for (int in = 0; in < 4; in++) {
        int r = n0 + in * 16 + rl;
        bOff[in] = 4096 + r * 32 + ((q ^ ((r >> 1) & 3)) << 3);
    }

    f32x4 acc[4][4];
#pragma unroll
    for (int a = 0; a < 4; a++)
#pragma unroll
        for (int b = 0; b < 4; b++)
            acc[a][b] = (f32x4){0.f, 0.f, 0.f, 0.f};

    for (int k0 = 0; k0 < H; k0 += GBK) {
        __syncthreads();
        GLD16(a0 + k0, lA0);
        GLD16(a1 + k0, lA1);
        GLD16(b0 + k0, lB0);
        GLD16(b1 + k0, lB1);
        __syncthreads();

        short8 aF[4], bF[4];
#pragma unroll
        for (int im = 0; im < 4; im++) aF[im] = *(const short8*)&lds[aOff[im]];
#pragma unroll
        for (int in = 0; in < 4; in++) bF[in] = *(const short8*)&lds[bOff[in]];

#pragma unroll
        for (int im = 0; im < 4; im++)
#pragma unroll
            for (int in = 0; in < 4; in++)
                acc[im][in] = __builtin_amdgcn_mfma_f32_16x16x32_bf16(
                    aF[im], bF[in], acc[im][in], 0, 0, 0);
    }

    // Epilogue: per-row partial (max, sumexp) over this wave's 64 cols.
    // C layout: row = m0 + im*16 + q*4 + i, col = n0 + in*16 + rl.
    const int chunk = (int)blockIdx.y * 2 + (n0 >> 6);
#pragma unroll
    for (int im = 0; im < 4; im++) {
#pragma unroll
        for (int i = 0; i < 4; i++) {
            float mx = fmaxf(fmaxf(acc[im][0][i], acc[im][1][i]),
                             fmaxf(acc[im][2][i], acc[im][3][i]));
#pragma unroll
            for (int off = 1; off < 16; off <<= 1)
                mx = fmaxf(mx, __shfl_xor(mx, off));
            float s = __expf(acc[im][0][i] - mx) + __expf(acc[im][1][i] - mx)
                    + __expf(acc[im][2][i] - mx) + __expf(acc[im][3][i] - mx);
#pragma unroll
            for (int off = 1; off < 16; off <<= 1)
                s += __shfl_xor(s, off);
            if (rl == 0) {
                int row = m0 + im * 16 + q * 4 + i;
                size_t idx = ((size_t)model * TOK + tokBase + row) * NCH + chunk;
                ms_m[idx] = mx;
                ms_s[idx] = s;
            }
        }
    }
}

// ---------------------------------------------------------------------------
// Round-1 fallback GEMM (known correct) — used only if ws too small.
// ---------------------------------------------------------------------------
__global__ __launch_bounds__(256) void gemm_partial(
    const float* __restrict__ X,  const float* __restrict__ Xr,
    const float* __restrict__ Wp, const float* __restrict__ Wr,
    float* __restrict__ ms_m, float* __restrict__ ms_s)
{
    __shared__ float smemF[64 * 65];
    short* smemS = (short*)smemF;
    short* ldsA = smemS;
    short* ldsB = smemS + 64 * 40;

    const int tid     = threadIdx.x;
    const int model   = blockIdx.z;
    const int tokBase = blockIdx.x * BM;
    const int vBase   = blockIdx.y * BN;

    const float* __restrict__ Xp = model ? Xr : X;
    const float* __restrict__ Wm = model ? Wr : Wp;

    const int lane = tid & 63;
    const int wave = tid >> 6;
    const int q    = lane >> 4;
    const int rl   = lane & 15;
    const int m0   = (wave >> 1) * 32;
    const int n0   = (wave & 1) * 32;

    f32x4 acc[2][2];
    for (int a = 0; a < 2; a++)
        for (int b = 0; b < 2; b++)
            acc[a][b] = (f32x4){0.f, 0.f, 0.f, 0.f};

    for (int kk = 0; kk < H / BK; kk++) {
        const int k0 = kk * BK;
        __syncthreads();
        for (int rep = 0; rep < 2; rep++) {
            int i   = tid + rep * 256;
            int row = i >> 3;
            int cf  = (i & 7) * 4;
            const float4 va = *(const float4*)(Xp + (size_t)(tokBase + row) * H + k0 + cf);
            short* pa = ldsA + row * 40 + cf;
            pa[0] = (short)f2bf(va.x); pa[1] = (short)f2bf(va.y);
            pa[2] = (short)f2bf(va.z); pa[3] = (short)f2bf(va.w);
            const float4 vb = *(const float4*)(Wm + (size_t)(vBase + row) * H + k0 + cf);
            short* pb = ldsB + row * 40 + cf;
            pb[0] = (short)f2bf(vb.x); pb[1] = (short)f2bf(vb.y);
            pb[2] = (short)f2bf(vb.z); pb[3] = (short)f2bf(vb.w);
        }
        __syncthreads();

        short8 aF[2], bF[2];
        for (int im = 0; im < 2; im++)
            aF[im] = *(const short8*)(ldsA + (m0 + im * 16 + rl) * 40 + q * 8);
        for (int in = 0; in < 2; in++)
            bF[in] = *(const short8*)(ldsB + (n0 + in * 16 + rl) * 40 + q * 8);

        for (int im = 0; im < 2; im++)
            for (int in = 0; in < 2; in++)
                acc[im][in] = __builtin_amdgcn_mfma_f32_16x16x32_bf16(
                    aF[im], bF[in], acc[im][in], 0, 0, 0);
    }

    __syncthreads();
    for (int im = 0; im < 2; im++)
        for (int in = 0; in < 2; in++)
            for (int i = 0; i < 4; i++)
                smemF[(m0 + im * 16 + q * 4 + i) * 65 + (n0 + in * 16 + rl)] =
                    acc[im][in][i];
    __syncthreads();

    if (tid < 64) {
        const float* rowp = smemF + tid * 65;
        float m = -INFINITY;
        for (int j = 0; j < 64; j++) m = fmaxf(m, rowp[j]);
        float s = 0.f;
        for (int j = 0; j < 64; j++) s += __expf(rowp[j] - m);
        size_t idx = ((size_t)model * TOK + (tokBase + tid)) * NCH + blockIdx.y;
        ms_m[idx] = m;
        ms_s[idx] = s;
    }
}

// ---------------------------------------------------------------------------
// Label logit per (model, token). One wave per token.
// ---------------------------------------------------------------------------
__global__ __launch_bounds__(256) void label_logit(
    const float* __restrict__ X,  const float* __restrict__ Xr,
    const float* __restrict__ Wp, const float* __restrict__ Wr,
    const int* __restrict__ y, float* __restrict__ z)
{
    int id    = blockIdx.x * 4 + (threadIdx.x >> 6);  // 0..4095
    int lane  = threadIdx.x & 63;
    int model = id >> 11;
    int token = id & 2047;
    const float* __restrict__ Xp = model ? Xr : X;
    const float* __restrict__ Wm = model ? Wr : Wp;
    int lab = y[token];
    float sum = 0.f;
    if (lab != IGN) {
        const float* xp = Xp + (size_t)token * H;
        const float* wp = Wm + (size_t)lab * H;
        for (int c = lane; c < H; c += 64) sum += xp[c] * wp[c];
    }
    for (int off = 32; off; off >>= 1) sum += __shfl_down(sum, off);
    if (lane == 0) z[id] = sum;
}

// ---------------------------------------------------------------------------
// Combine 500 partial (m,s) per (model,token) -> logp.
// ---------------------------------------------------------------------------
__global__ __launch_bounds__(256) void lse_logp(
    const float* __restrict__ ms_m, const float* __restrict__ ms_s,
    const float* __restrict__ z, float* __restrict__ logp)
{
    int id = blockIdx.x;   // 0..4095
    int t  = threadIdx.x;
    __shared__ float red[256];
    const float* mrow = ms_m + (size_t)id * NCH;
    const float* srow = ms_s + (size_t)id * NCH;

    float m = -INFINITY;
    for (int c = t; c < NCH; c += 256) m = fmaxf(m, mrow[c]);
    red[t] = m; __syncthreads();
    for (int w = 128; w; w >>= 1) {
        if (t < w) red[t] = fmaxf(red[t], red[t + w]);
        __syncthreads();
    }
    float M = red[0]; __syncthreads();

    float s = 0.f;
    for (int c = t; c < NCH; c += 256) s += srow[c] * __expf(mrow[c] - M);
    red[t] = s; __syncthreads();
    for (int w = 128; w; w >>= 1) {
        if (t < w) red[t] += red[t + w];
        __syncthreads();
    }
    if (t == 0) {
        float lse = M + logf(red[0]);
        logp[id] = z[id] - lse;
    }
}

// ---------------------------------------------------------------------------
// Batch means + SPPO-hard loss. 1 block.
// ---------------------------------------------------------------------------
__global__ void final_loss(const float* __restrict__ logp,
                           const int* __restrict__ y,
                           float* __restrict__ out)
{
    __shared__ float lp[8];
    int t = threadIdx.x;
    if (t < 8) {
        int model = t >> 2, b = t & 3;
        float s = 0.f, cnt = 0.f;
        for (int i = 0; i < T; i++) {
            int tok = b * T + i;
            if (y[tok] != IGN) { s += logp[model * TOK + tok]; cnt += 1.f; }
        }
        lp[t] = s / cnt;
    }
    __syncthreads();
    if (t == 0) {
        float a0 = lp[0] - lp[4], a1 = lp[1] - lp[5];
        float b0 = lp[2] - lp[6], b1 = lp[3] - lp[7];
        float l0 = (a0 - 5.f) * (a0 - 5.f) + (b0 + 5.f) * (b0 + 5.f);
        float l1 = (a1 - 5.f) * (a1 - 5.f) + (b1 + 5.f) * (b1 + 5.f);
        out[0] = -(l0 + l1) * 0.5f;
    }
}

extern "C" void kernel_launch(void* const* d_in, const int* in_sizes, int n_in,
                              void* d_out, int out_size, void* d_ws, size_t ws_size,
                              hipStream_t stream)
{
    const float* X  = (const float*)d_in[0];
    const float* Xr = (const float*)d_in[1];
    const int*   y  = (const int*)d_in[2];
    const float* Wp = (const float*)d_in[3];
    const float* Wr = (const float*)d_in[4];
    float* out = (float*)d_out;

    // shared ws layout (floats first, then bf16 arrays for fast path)
    float* ws   = (float*)d_ws;
    const size_t msElems = (size_t)2 * TOK * NCH;   // 2,048,000
    float* ms_m = ws;
    float* ms_s = ws + msElems;
    float* z    = ws + 2 * msElems;
    float* logp = z + 2 * TOK;
    u16*   Xb   = (u16*)(logp + 2 * TOK);
    u16*   Wb   = Xb + (size_t)2 * 2048 * H;        // + 8,388,608 shorts

    const size_t NEED = 2 * msElems * 4 + 4 * 2 * TOK * 4
                      + (size_t)2 * 2048 * H * 2 + (size_t)2 * V * H * 2;

    if (ws_size >= NEED) {
        // fast path: pre-convert to bf16, then m97-structure GEMM
        f32_to_bf16<<<1024, 256, 0, stream>>>(X,  Xb,                 (2048 * H) / 4);
        f32_to_bf16<<<1024, 256, 0, stream>>>(Xr, Xb + 2048 * H,      (2048 * H) / 4);
        f32_to_bf16<<<4096, 256, 0, stream>>>(Wp, Wb,                 (V * H) / 4);
        f32_to_bf16<<<4096, 256, 0, stream>>>(Wr, Wb + (size_t)V * H, (V * H) / 4);

        dim3 gg(TOK / GBM, V / GBN, 2);    // (16, 250, 2)
        gemm_bf16<<<gg, 256, 0, stream>>>(Xb, Wb, ms_m, ms_s);
    } else {
        // fallback: round-1 known-correct path
        dim3 g1(TOK / BM, V / BN, 2);      // (32, 500, 2)
        gemm_partial<<<g1, 256, 0, stream>>>(X, Xr, Wp, Wr, ms_m, ms_s);
    }

    label_logit<<<(2 * TOK) / 4, 256, 0, stream>>>(X, Xr, Wp, Wr, y, z);
    lse_logp<<<2 * TOK, 256, 0, stream>>>(ms_m, ms_s, z, logp);
    final_loss<<<1, 64, 0, stream>>>(logp, y, out);
}